// Round 11
// baseline (105.369 us; speedup 1.0000x reference)
//
#include <hip/hip_runtime.h>

// GATv1-style single-head attention, N=8192, F_in=128, F_out=64, alpha=0.2.
// exp(leakyrelu(s_i + d_j)) is separable per branch; predicate fl(s+d)>0 is
// exactly mono_enc(d) > mono_enc(-s). Sort j by d, prefix tables of e^d*Wh and
// e^{0.2d}*Wh sampled every 8 sorted elements, per-row ballot search + <=7
// residual terms. O(N^2 F) -> O(N(logN+F)).
// ROOT CAUSE of every r5-r8/r10 abort (found r10 post-mortem): the branchless
// 8-step binary count (steps 128..1) saturates at 255, but a fully-smaller run
// has count 256 -> rank collisions -> unwritten keyB slots keep 0xAA poison ->
// j=0xAAAAAAAA -> Wh gather ~733GB OOB -> memory fault -> HSA abort. Fixed with
// a run[255] pre-check; all key-decoded j's are also masked to [0,8191] so any
// future rank bug shows up as absmax error, not a crash.
// Other constraints (verified): no cooperative launch, no memset in
// kernel_launch, no software grid barriers. Plain dispatches only.

typedef unsigned long long ull;

constexpr int N_ROWS = 8192;
constexpr int F_IN   = 128;
constexpr int F_OUT  = 64;
#define LRELU_ALPHA 0.2f

constexpr int SBLK = 8;                  // prefix-table sampling granularity
constexpr int NGRP = N_ROWS / SBLK;      // 1024 groups; tables hold NGRP+1 entries

// workspace layout in floats (~2.8 MB)
constexpr int WS_WH   = 0;                          // Wh row-major [j][c]
constexpr int WS_ESRC = WS_WH + N_ROWS * F_OUT;     // e_src[i]
constexpr int WS_KEYA = WS_ESRC + N_ROWS;           // 8192 ull: 32 sorted runs of 256
constexpr int WS_KEYB = WS_KEYA + 2 * N_ROWS;       // 8192 ull: fully sorted
constexpr int WS_P1   = WS_KEYB + 2 * N_ROWS;       // (NGRP+1) x 64, layout [b][c]
constexpr int WS_P2   = WS_P1 + (NGRP + 1) * F_OUT;
constexpr int WS_D1   = WS_P2 + (NGRP + 1) * F_OUT; // NGRP+1
constexpr int WS_D2   = WS_D1 + (NGRP + 1);
static_assert((WS_KEYA % 2) == 0 && (WS_KEYB % 2) == 0, "keys 8B-aligned");

__device__ __forceinline__ unsigned mono_enc(float f) {
  unsigned u = __float_as_uint(f);
  return u ^ ((u & 0x80000000u) ? 0xFFFFFFFFu : 0x80000000u);
}
__device__ __forceinline__ float mono_dec(unsigned e) {
  unsigned u = e ^ ((e & 0x80000000u) ? 0x80000000u : 0xFFFFFFFFu);
  return __uint_as_float(u);
}

// ---------------- K1: Wh = h @ W ; e_src = Wh@a1 ; keys = (enc(Wh@a2), j) ----------------
// grid 512 x 256 threads. 16 rows/block, wave handles 4 rows, lane = output col. (proven)
__global__ __launch_bounds__(256) void k1_wh(const float* __restrict__ h,
                                             const float* __restrict__ W,
                                             const float* __restrict__ a,
                                             float* __restrict__ ws) {
  __shared__ float hlds[16 * F_IN];
  __shared__ float alds[2 * F_OUT];
  const int t = threadIdx.x;
  const int row0 = blockIdx.x * 16;

  const float4* hsrc = (const float4*)(h + (long)row0 * F_IN);
  float4* hd = (float4*)hlds;
  hd[t]       = hsrc[t];
  hd[t + 256] = hsrc[t + 256];
  if (t < 2 * F_OUT) alds[t] = a[t];
  __syncthreads();

  const int wave = t >> 6, lane = t & 63;
  const float* hp = hlds + (wave * 4) * F_IN;
  float acc0 = 0.f, acc1 = 0.f, acc2 = 0.f, acc3 = 0.f;

  #pragma unroll 4
  for (int k4 = 0; k4 < F_IN; k4 += 4) {
    float4 h0 = *(const float4*)(hp + k4);
    float4 h1 = *(const float4*)(hp + F_IN + k4);
    float4 h2 = *(const float4*)(hp + 2 * F_IN + k4);
    float4 h3 = *(const float4*)(hp + 3 * F_IN + k4);
    float w0 = W[(k4 + 0) * F_OUT + lane];
    float w1 = W[(k4 + 1) * F_OUT + lane];
    float w2 = W[(k4 + 2) * F_OUT + lane];
    float w3 = W[(k4 + 3) * F_OUT + lane];
    acc0 = fmaf(h0.x, w0, acc0); acc0 = fmaf(h0.y, w1, acc0);
    acc0 = fmaf(h0.z, w2, acc0); acc0 = fmaf(h0.w, w3, acc0);
    acc1 = fmaf(h1.x, w0, acc1); acc1 = fmaf(h1.y, w1, acc1);
    acc1 = fmaf(h1.z, w2, acc1); acc1 = fmaf(h1.w, w3, acc1);
    acc2 = fmaf(h2.x, w0, acc2); acc2 = fmaf(h2.y, w1, acc2);
    acc2 = fmaf(h2.z, w2, acc2); acc2 = fmaf(h2.w, w3, acc2);
    acc3 = fmaf(h3.x, w0, acc3); acc3 = fmaf(h3.y, w1, acc3);
    acc3 = fmaf(h3.z, w2, acc3); acc3 = fmaf(h3.w, w3, acc3);
  }

  const int grow = row0 + wave * 4;
  float* Wh = ws + WS_WH;
  Wh[(grow + 0) * F_OUT + lane] = acc0;
  Wh[(grow + 1) * F_OUT + lane] = acc1;
  Wh[(grow + 2) * F_OUT + lane] = acc2;
  Wh[(grow + 3) * F_OUT + lane] = acc3;

  const float a1 = alds[lane], a2 = alds[F_OUT + lane];
  float s0 = acc0 * a1, s1 = acc1 * a1, s2 = acc2 * a1, s3 = acc3 * a1;
  float d0 = acc0 * a2, d1 = acc1 * a2, d2 = acc2 * a2, d3 = acc3 * a2;
  #pragma unroll
  for (int off = 32; off; off >>= 1) {
    s0 += __shfl_down(s0, off); s1 += __shfl_down(s1, off);
    s2 += __shfl_down(s2, off); s3 += __shfl_down(s3, off);
    d0 += __shfl_down(d0, off); d1 += __shfl_down(d1, off);
    d2 += __shfl_down(d2, off); d3 += __shfl_down(d3, off);
  }
  if (lane == 0) {
    ws[WS_ESRC + grow + 0] = s0; ws[WS_ESRC + grow + 1] = s1;
    ws[WS_ESRC + grow + 2] = s2; ws[WS_ESRC + grow + 3] = s3;
    ull* keys = (ull*)(ws + WS_KEYA);
    keys[grow + 0] = ((ull)mono_enc(d0) << 32) | (unsigned)(grow + 0);
    keys[grow + 1] = ((ull)mono_enc(d1) << 32) | (unsigned)(grow + 1);
    keys[grow + 2] = ((ull)mono_enc(d2) << 32) | (unsigned)(grow + 2);
    keys[grow + 3] = ((ull)mono_enc(d3) << 32) | (unsigned)(grow + 3);
  }
}

// ---------------- K2a: 32 blocks, each bitonic-sorts a 256-key chunk in LDS (proven) -----
__global__ __launch_bounds__(256) void k2a_local(ull* __restrict__ keys) {
  __shared__ ull lk[256];
  const int t = threadIdx.x;
  const int base = blockIdx.x * 256;
  lk[t] = keys[base + t];
  __syncthreads();
  for (int k = 2; k <= 256; k <<= 1) {
    for (int j = k >> 1; j > 0; j >>= 1) {
      int p = t ^ j;
      if (p > t) {
        ull x = lk[t], y = lk[p];
        bool asc = ((t & k) == 0);
        if ((x > y) == asc) { lk[t] = y; lk[p] = x; }
      }
      __syncthreads();
    }
  }
  keys[base + t] = lk[t];
}

// ---------------- K2b: ONE 32-way merge-scatter keyA -> keyB ----------------
// grid 256 x 256 (65536 threads). 8 threads per element; each counts rank in 4
// of the 32 sorted runs, __shfl_down combine in the aligned 8-lane group, sub 0
// scatters. Count per run: pre-check run[255] (count==256 case -- THE r5-r10
// crash bug), else branchless 8-step search (exact for counts <= 255).
// Keys unique (low bits = j) -> ranks form a bijection onto [0,8192).
__global__ __launch_bounds__(256) void k_merge32(const ull* __restrict__ keyA,
                                                 ull* __restrict__ keyB) {
  const int gt = blockIdx.x * 256 + threadIdx.x;
  const int elem = gt >> 3, sub = gt & 7;
  const ull key = keyA[elem];
  const int r0 = elem >> 8;
  int cnt = 0;
  #pragma unroll
  for (int rr = 0; rr < 4; ++rr) {
    const int r = sub * 4 + rr;
    if (r == r0) continue;
    const ull* run = keyA + (r << 8);
    if (run[255] < key) {              // whole run below key: count = 256
      cnt += 256;
    } else {                           // count <= 255: branchless exact
      int lo = 0;
      #pragma unroll
      for (int step = 128; step; step >>= 1)
        lo += (run[lo + step - 1] < key) ? step : 0;
      cnt += lo;
    }
  }
  cnt += __shfl_down(cnt, 4);
  cnt += __shfl_down(cnt, 2);
  cnt += __shfl_down(cnt, 1);
  if (sub == 0) keyB[cnt + (elem & 255)] = key;
}

// ---------------- K3: fused per-column prefix tables (65 blocks) ----------------
// Block c (<64): thread t owns groups [4t,4t+4) (32 consecutive sorted elements);
// computes e^d and e^{0.2d} group sums for column c, float2 LDS Hillis-Steele
// scan over the 256 thread totals, writes exclusive entries + total.
// Block 64: scalar denominators (v = 1).
__global__ __launch_bounds__(256) void k3_tables(float* __restrict__ ws) {
  __shared__ float2 sm[256];
  const ull* keyB = (const ull*)(ws + WS_KEYB);
  const float* Wh = ws + WS_WH;
  const int t = threadIdx.x;
  const int c = blockIdx.x;
  const bool isD = (c == F_OUT);

  float g1[4], g2[4];
  for (int gg = 0; gg < 4; ++gg) {
    const int g = t * 4 + gg;
    float s1 = 0.f, s2 = 0.f;
    #pragma unroll
    for (int o = 0; o < SBLK; ++o) {
      ull key = keyB[(g << 3) + o];
      float d = mono_dec((unsigned)(key >> 32));
      int j = (int)(key & 0xFFFFFFFFu) & (N_ROWS - 1);   // mask: fault -> absmax
      float e1 = __expf(d), e2 = __expf(LRELU_ALPHA * d);
      float v = isD ? 1.0f : Wh[j * F_OUT + c];
      s1 = fmaf(e1, v, s1); s2 = fmaf(e2, v, s2);
    }
    g1[gg] = s1; g2[gg] = s2;
  }
  const float tot1 = g1[0] + g1[1] + g1[2] + g1[3];
  const float tot2 = g2[0] + g2[1] + g2[2] + g2[3];
  sm[t] = make_float2(tot1, tot2);
  __syncthreads();
  for (int off = 1; off < 256; off <<= 1) {          // inclusive scan
    float2 y = (t >= off) ? sm[t - off] : make_float2(0.f, 0.f);
    __syncthreads();
    sm[t].x += y.x; sm[t].y += y.y;
    __syncthreads();
  }
  float p1 = sm[t].x - tot1, p2 = sm[t].y - tot2;    // exclusive offsets
  for (int gg = 0; gg < 4; ++gg) {
    const int g = t * 4 + gg;
    if (!isD) {
      ws[WS_P1 + g * F_OUT + c] = p1;
      ws[WS_P2 + g * F_OUT + c] = p2;
    } else {
      ws[WS_D1 + g] = p1;
      ws[WS_D2 + g] = p2;
    }
    p1 += g1[gg]; p2 += g2[gg];
  }
  if (t == 255) {
    if (!isD) {
      ws[WS_P1 + NGRP * F_OUT + c] = p1;
      ws[WS_P2 + NGRP * F_OUT + c] = p2;
    } else {
      ws[WS_D1 + NGRP] = p1;
      ws[WS_D2 + NGRP] = p2;
    }
  }
}

// ---------------- K4: 3-stage wave-ballot search + table lookup + residual + ELU ---------
// grid 2048 x 256. One wave per row, lane = output column. (proven)
__global__ __launch_bounds__(256) void k4_out(const float* __restrict__ ws,
                                              float* __restrict__ out) {
  const int t = threadIdx.x, wv = t >> 6, lane = t & 63;
  const int i = blockIdx.x * 4 + wv;
  const ull* K = (const ull*)(ws + WS_KEYB);
  const float s = ws[WS_ESRC + i];
  const float ns = (s == 0.0f) ? 0.0f : -s;   // canonicalize -0
  const unsigned Ki = mono_enc(ns);           // m > Ki  <=>  fl(s+d) > 0

  unsigned m1 = (unsigned)(K[lane << 7] >> 32);
  ull bal1 = __ballot(m1 <= Ki);
  int tl;
  if (bal1 == 0ull) {
    tl = 0;
  } else {
    int L1 = 63 - __clzll((long long)bal1);
    int base = L1 << 7;
    unsigned m2 = (unsigned)(K[base + (lane << 1)] >> 32);
    ull bal2 = __ballot(m2 <= Ki);
    int L2 = 63 - __clzll((long long)bal2);
    int p = base + (L2 << 1) + 1;
    unsigned m3 = (unsigned)(K[p] >> 32);
    tl = p + ((m3 <= Ki) ? 1 : 0);
  }
  const int b = tl >> 3, rr = tl & 7;

  float p1 = ws[WS_P1 + b * F_OUT + lane];
  float p2 = ws[WS_P2 + b * F_OUT + lane];
  float d1 = ws[WS_D1 + b], d2 = ws[WS_D2 + b];
  const float p1tot = ws[WS_P1 + NGRP * F_OUT + lane];
  const float d1tot = ws[WS_D1 + NGRP];
  const float* Wh = ws + WS_WH;

  for (int o = 0; o < rr; ++o) {               // <=7 residual elements
    ull key = K[(b << 3) + o];
    float d = mono_dec((unsigned)(key >> 32));
    int j = (int)(key & 0xFFFFFFFFu) & (N_ROWS - 1);   // mask: fault -> absmax
    float e1 = __expf(d), e2 = __expf(LRELU_ALPHA * d);
    float v = Wh[j * F_OUT + lane];            // coalesced 256B row
    p1 = fmaf(e1, v, p1); p2 = fmaf(e2, v, p2);
    d1 += e1; d2 += e2;
  }

  const float es1 = __expf(s), es2 = __expf(LRELU_ALPHA * s);
  const float num = es1 * (p1tot - p1) + es2 * p2;
  const float den = es1 * (d1tot - d1) + es2 * d2;
  const float r = num / den;
  out[i * F_OUT + lane] = (r > 0.f) ? r : (__expf(r) - 1.f);
}

extern "C" void kernel_launch(void* const* d_in, const int* in_sizes, int n_in,
                              void* d_out, int out_size, void* d_ws, size_t ws_size,
                              hipStream_t stream) {
  const float* h = (const float*)d_in[0];
  const float* W = (const float*)d_in[1];
  const float* a = (const float*)d_in[2];
  float* ws = (float*)d_ws;
  float* out = (float*)d_out;
  ull* keyA = (ull*)(ws + WS_KEYA);
  ull* keyB = (ull*)(ws + WS_KEYB);

  hipLaunchKernelGGL(k1_wh,     dim3(N_ROWS / 16), dim3(256), 0, stream, h, W, a, ws);
  hipLaunchKernelGGL(k2a_local, dim3(32),          dim3(256), 0, stream, keyA);
  hipLaunchKernelGGL(k_merge32, dim3(256),         dim3(256), 0, stream, keyA, keyB);
  hipLaunchKernelGGL(k3_tables, dim3(F_OUT + 1),   dim3(256), 0, stream, ws);
  hipLaunchKernelGGL(k4_out,    dim3(N_ROWS / 4),  dim3(256), 0, stream, ws, out);
}